// Round 16
// baseline (351.357 us; speedup 1.0000x reference)
//
#include <hip/hip_runtime.h>
#include <hip/hip_bf16.h>

#define NN   8192
#define INF_ 256
#define OUTF 128
#define SLOPE 0.2f
#define NCH  2               // chunks per block
#define CHJ  2048            // j per chunk
#define NT_  16              // tiles per chunk (128 j each)

typedef float f32x4  __attribute__((ext_vector_type(4)));
typedef float f32x16 __attribute__((ext_vector_type(16)));
typedef short bf16x8 __attribute__((ext_vector_type(8)));
typedef int   i32x4  __attribute__((ext_vector_type(4)));
typedef unsigned int u32;
typedef unsigned short u16;
typedef u16 u16x2 __attribute__((ext_vector_type(2)));

__device__ __forceinline__ u16 f2bf(float f) {
  return __builtin_bit_cast(u16, __float2bfloat16(f));
}

// j mapping: j = cc*2048 + tt*128 + ks*16 + g*8 + e
//   (cc 0..3 global chunk, tt 0..15 tile, ks 0..7 k-slice, g lane>>5, e 0..7)
// hbF B-frag block n = (cc*16 + tt)*8 + ks; element (n,q,l,e) at
//   ((n*4+q)*64 + l)*8 + e   (q = col>>5).
// Mask byte (row, cc, tt, ks, g) at
//   mb[cc&1][row*256 + ((ks^(row&7))<<5) + g*16 + tt].

// ---------------------------------------------------------------------------
// K1: h = X @ W (fp32). 512 blocks x 16 rows. Writes hbF (B-frag order),
// s1, s2 (plain j order).
// ---------------------------------------------------------------------------
__global__ __launch_bounds__(256) void gat_k1(
    const float* __restrict__ X, const float* __restrict__ W,
    const float* __restrict__ a, u16* __restrict__ hbF,
    float* __restrict__ s1, float* __restrict__ s2) {
  __shared__ float xs[16 * INF_];
  const int t = threadIdx.x;
  const int r0 = blockIdx.x * 16;
  {
    const f32x4* src = (const f32x4*)(X + (size_t)r0 * INF_);
    f32x4* dst = (f32x4*)xs;
#pragma unroll
    for (int i = 0; i < 4; i++) dst[t + 256 * i] = src[t + 256 * i];
  }
  __syncthreads();
  const int cg = t & 31;
  const int rg = t >> 5;
  float acc[2][4];
#pragma unroll
  for (int i = 0; i < 2; i++)
#pragma unroll
    for (int j = 0; j < 4; j++) acc[i][j] = 0.f;

  for (int k = 0; k < INF_; k += 4) {
    f32x4 xv[2];
#pragma unroll
    for (int i = 0; i < 2; i++) xv[i] = *(const f32x4*)&xs[(rg * 2 + i) * INF_ + k];
#pragma unroll
    for (int kk = 0; kk < 4; kk++) {
      f32x4 wv = *(const f32x4*)&W[(k + kk) * OUTF + cg * 4];
#pragma unroll
      for (int i = 0; i < 2; i++)
#pragma unroll
        for (int j = 0; j < 4; j++) acc[i][j] = fmaf(xv[i][kk], wv[j], acc[i][j]);
    }
  }

  f32x4 a1v = *(const f32x4*)&a[cg * 4];
  f32x4 a2v = *(const f32x4*)&a[OUTF + cg * 4];
  float p1[2], p2[2];
#pragma unroll
  for (int i = 0; i < 2; i++) {
    p1[i] = acc[i][0] * a1v[0] + acc[i][1] * a1v[1] + acc[i][2] * a1v[2] + acc[i][3] * a1v[3];
    p2[i] = acc[i][0] * a2v[0] + acc[i][1] * a2v[1] + acc[i][2] * a2v[2] + acc[i][3] * a2v[3];
  }
#pragma unroll
  for (int m = 1; m < 32; m <<= 1) {
#pragma unroll
    for (int i = 0; i < 2; i++) {
      p1[i] += __shfl_xor(p1[i], m);
      p2[i] += __shfl_xor(p2[i], m);
    }
  }
  if (cg == 0) {
#pragma unroll
    for (int i = 0; i < 2; i++) {
      s1[r0 + rg * 2 + i] = p1[i];
      s2[r0 + rg * 2 + i] = p2[i];
    }
  }

  const int R0 = r0 + rg * 2;           // 2-aligned
  const int cc = R0 >> 11;
  const int tt = (R0 >> 7) & 15;
  const int ks = (R0 >> 4) & 7;
  const int gg = (R0 >> 3) & 1;
  const int e0 = R0 & 7;
  const int n  = (cc * 16 + tt) * 8 + ks;
#pragma unroll
  for (int j = 0; j < 4; j++) {
    const int C = cg * 4 + j;
    u16x2 pk = {f2bf(acc[0][j]), f2bf(acc[1][j])};
    *(u16x2*)(hbF + ((size_t)(n * 4 + (C >> 5)) * 64 + gg * 32 + (C & 31)) * 8 + e0) = pk;
  }
}

// ---------------------------------------------------------------------------
// K2: E1 = exp(s2); E2 = exp(SLOPE*s2); bmax[block] = max chunk.
// ---------------------------------------------------------------------------
__global__ __launch_bounds__(256) void gat_k2(const float* __restrict__ s2,
                                              float* __restrict__ bmax,
                                              float* __restrict__ E1,
                                              float* __restrict__ E2) {
  __shared__ float sm[4];
  const int t = threadIdx.x;
  const int i = blockIdx.x * 256 + t;
  f32x4 v = ((const f32x4*)s2)[i];
  f32x4 e1, e2;
  float m = -1e30f;
#pragma unroll
  for (int k = 0; k < 4; k++) {
    m = fmaxf(m, v[k]);
    e1[k] = __expf(v[k]);
    e2[k] = __expf(SLOPE * v[k]);
  }
  ((f32x4*)E1)[i] = e1;
  ((f32x4*)E2)[i] = e2;
#pragma unroll
  for (int k = 1; k < 64; k <<= 1) m = fmaxf(m, __shfl_xor(m, k));
  if ((t & 63) == 0) sm[t >> 6] = m;
  __syncthreads();
  if (t == 0)
    bmax[blockIdx.x] = fmaxf(fmaxf(sm[0], sm[1]), fmaxf(sm[2], sm[3]));
}

// ---------------------------------------------------------------------------
// K3: 512 blocks x 512 thr, TRUE 2 blocks/CU under launch_bounds(512,4):
// wave w = (kpair = w>>1, chalf = w&1) computes only 64 output cols
// (acc = 2 x f32x16 = 32 regs) for k-slices {kpair, kpair+4} -> total live
// ~117 regs < 128 cap (R13/R14 spilled because acc=64 + staging > 128).
// Chunk-level double buffer: compute chunk c while streaming+packing c+1;
// 1 stage-step per tile (16:16); one barrier per chunk, loads all consumed.
// ---------------------------------------------------------------------------
__device__ __forceinline__ void st16(float* dst, const f32x16& A, int g) {
#pragma unroll
  for (int r = 0; r < 16; r++) {
    const int dr = (r & 3) + 8 * (r >> 2) + 4 * g;
    dst[dr * 128] = A[r];
  }
}
__device__ __forceinline__ void ad16(float* dst, const f32x16& A, int g) {
#pragma unroll
  for (int r = 0; r < 16; r++) {
    const int dr = (r & 3) + 8 * (r >> 2) + 4 * g;
    dst[dr * 128] += A[r];
  }
}

__global__ __launch_bounds__(512, 4) void gat_k3(
    const int* __restrict__ adj, const u16* __restrict__ hbF,
    const float* __restrict__ s1g, const float* __restrict__ E1,
    const float* __restrict__ E2, const float* __restrict__ bmax,
    float* __restrict__ part, float* __restrict__ dpart) {
  __shared__ unsigned char mb[2][8192];  // mask double-buffer (32 x 256 B)
  __shared__ float lred[4096];           // 16 KB single reduce buffer
  __shared__ float dred[128];
  const int t = threadIdx.x;
  const int w = t >> 6;
  const int l = t & 63;
  const int kpair = w >> 1;     // 0..3: k-slices {kpair, kpair+4}
  const int chalf = w & 1;      // 0..1: output cols [chalf*64, +64)
  const int rb = blockIdx.x >> 1;
  const int jh = blockIdx.x & 1;
  const int r0 = rb * 32;
  const int row = l & 31;
  const int g = l >> 5;

  // ---- per-row constants ----
  float s2m = bmax[0];
#pragma unroll
  for (int k = 1; k < 8; k++) s2m = fmaxf(s2m, bmax[k]);
  const float s1r = s1g[r0 + row];
  float Mi = s1r + s2m;
  Mi = fmaxf(Mi, SLOPE * Mi);
  const float A = __expf(s1r - Mi);
  const float B = __expf(SLOPE * s1r - Mi);

  // ---- staging ids: thread (srow = t>>4, cl = t&15); step = 8 ints ----
  const int srow = t >> 4;
  const int cl = t & 15;
  const int* gsrc = adj + (size_t)(r0 + srow) * NN + jh * (NCH * CHJ) + cl * 8;

  i32x4 sA0, sA1, sB0, sB1;
#define LOADP(S0, S1, C, K)                                  \
  {                                                          \
    const int* p_ = gsrc + (C) * CHJ + (K) * 128;            \
    S0 = *(const i32x4*)(p_);                                \
    S1 = *(const i32x4*)(p_ + 4);                            \
  }
  // 8-int group (K, cl): idx = K*16+cl -> tt = idx>>4, ks = (idx>>1)&7, gb = idx&1
#define PACKP(S0, S1, K, NB)                                                   \
  {                                                                            \
    const int idx_ = (K)*16 + cl;                                              \
    const int tt_ = idx_ >> 4;                                                 \
    const int ks_ = (idx_ >> 1) & 7;                                           \
    const int gb_ = idx_ & 1;                                                  \
    unsigned b_ = 0;                                                           \
    _Pragma("unroll") for (int e_ = 0; e_ < 4; e_++) {                         \
      b_ |= (S0[e_] > 0 ? 1u : 0u) << e_;                                      \
      b_ |= (S1[e_] > 0 ? 1u : 0u) << (e_ + 4);                                \
    }                                                                          \
    mb[NB][srow * 256 + ((ks_ ^ (srow & 7)) << 5) + gb_ * 16 + tt_] =          \
        (unsigned char)b_;                                                     \
  }

  f32x16 accQ0 = 0.f, accQ1 = 0.f;
  float dsum = 0.f;

#define COMPUTE(CC, TT, BLO, BHI)                                              \
  {                                                                            \
    const unsigned bl_ = ((unsigned)(BLO)[(TT) >> 2] >> (((TT)&3) * 8)) & 0xffu; \
    const unsigned bh_ = ((unsigned)(BHI)[(TT) >> 2] >> (((TT)&3) * 8)) & 0xffu; \
    const int n0 = ((CC)*16 + (TT)) * 8 + kpair;                               \
    const u16* q0 = hbF + (size_t)n0 * 2048 + chalf * 1024 + l * 8;            \
    bf16x8 b00 = *(const bf16x8*)(q0);                                         \
    bf16x8 b01 = *(const bf16x8*)(q0 + 512);                                   \
    const u16* q1 = q0 + 4 * 2048;                                             \
    bf16x8 b10 = *(const bf16x8*)(q1);                                         \
    bf16x8 b11 = *(const bf16x8*)(q1 + 512);                                   \
    const int j0 = (CC)*CHJ + (TT)*128 + kpair * 16 + g * 8;                   \
    f32x4 u0 = *(const f32x4*)(E1 + j0);                                       \
    f32x4 u1 = *(const f32x4*)(E1 + j0 + 4);                                   \
    f32x4 v0 = *(const f32x4*)(E2 + j0);                                       \
    f32x4 v1 = *(const f32x4*)(E2 + j0 + 4);                                   \
    f32x4 u2 = *(const f32x4*)(E1 + j0 + 64);                                  \
    f32x4 u3 = *(const f32x4*)(E1 + j0 + 68);                                  \
    f32x4 v2 = *(const f32x4*)(E2 + j0 + 64);                                  \
    f32x4 v3 = *(const f32x4*)(E2 + j0 + 68);                                  \
    u32 a0w[4], a1w[4];                                                        \
    _Pragma("unroll") for (int e = 0; e < 8; e += 2) {                         \
      const float x0 = (e < 4) ? u0[e & 3] : u1[e & 3];                        \
      const float x1 = (e < 4) ? u0[(e + 1) & 3] : u1[(e + 1) & 3];            \
      const float y0 = (e < 4) ? v0[e & 3] : v1[e & 3];                        \
      const float y1 = (e < 4) ? v0[(e + 1) & 3] : v1[(e + 1) & 3];            \
      float pa = fmaxf(A * x0, B * y0);                                        \
      float pb = fmaxf(A * x1, B * y1);                                        \
      pa = (bl_ & (1u << e)) ? pa : 0.f;                                       \
      pb = (bl_ & (1u << (e + 1))) ? pb : 0.f;                                 \
      dsum += pa + pb;                                                         \
      a0w[e >> 1] = __builtin_amdgcn_perm(                                     \
          __builtin_bit_cast(u32, pb) + 0x8000u,                               \
          __builtin_bit_cast(u32, pa) + 0x8000u, 0x07060302u);                 \
      const float x2 = (e < 4) ? u2[e & 3] : u3[e & 3];                        \
      const float x3 = (e < 4) ? u2[(e + 1) & 3] : u3[(e + 1) & 3];            \
      const float y2 = (e < 4) ? v2[e & 3] : v3[e & 3];                        \
      const float y3 = (e < 4) ? v2[(e + 1) & 3] : v3[(e + 1) & 3];            \
      float pc = fmaxf(A * x2, B * y2);                                        \
      float pd = fmaxf(A * x3, B * y3);                                        \
      pc = (bh_ & (1u << e)) ? pc : 0.f;                                       \
      pd = (bh_ & (1u << (e + 1))) ? pd : 0.f;                                 \
      dsum += pc + pd;                                                         \
      a1w[e >> 1] = __builtin_amdgcn_perm(                                     \
          __builtin_bit_cast(u32, pd) + 0x8000u,                               \
          __builtin_bit_cast(u32, pc) + 0x8000u, 0x07060302u);                 \
    }                                                                          \
    const bf16x8 af0 = __builtin_bit_cast(                                     \
        bf16x8, (i32x4){(int)a0w[0], (int)a0w[1], (int)a0w[2], (int)a0w[3]});  \
    const bf16x8 af1 = __builtin_bit_cast(                                     \
        bf16x8, (i32x4){(int)a1w[0], (int)a1w[1], (int)a1w[2], (int)a1w[3]});  \
    accQ0 = __builtin_amdgcn_mfma_f32_32x32x16_bf16(af0, b00, accQ0, 0, 0, 0); \
    accQ1 = __builtin_amdgcn_mfma_f32_32x32x16_bf16(af0, b01, accQ1, 0, 0, 0); \
    accQ0 = __builtin_amdgcn_mfma_f32_32x32x16_bf16(af1, b10, accQ0, 0, 0, 0); \
    accQ1 = __builtin_amdgcn_mfma_f32_32x32x16_bf16(af1, b11, accQ1, 0, 0, 0); \
  }

  // ---- prologue: stream local chunk 0 into mb[0] ----
  LOADP(sA0, sA1, 0, 0);
  LOADP(sB0, sB1, 0, 1);
#pragma unroll
  for (int p = 2; p < NT_; p += 2) {
    PACKP(sA0, sA1, p - 2, 0);
    LOADP(sA0, sA1, 0, p);
    PACKP(sB0, sB1, p - 1, 0);
    LOADP(sB0, sB1, 0, p + 1);
  }
  PACKP(sA0, sA1, 14, 0);
  PACKP(sB0, sB1, 15, 0);
  __syncthreads();

  // ---- main: runtime loop over 2 local chunks ----
  for (int c = 0; c < NCH; c++) {
    const int cb = c & 1, nb = cb ^ 1;
    const int cc = jh * NCH + c;
    const unsigned char* mrow = &mb[cb][row * 256 + g * 16];
    const i32x4 blo = *(const i32x4*)(mrow + ((kpair ^ (row & 7)) << 5));
    const i32x4 bhi = *(const i32x4*)(mrow + (((kpair + 4) ^ (row & 7)) << 5));
    const bool more = (c + 1 < NCH);

#pragma unroll
    for (int q4 = 0; q4 < 4; q4++) {
#pragma unroll
      for (int ti = 0; ti < 4; ti++) {
        const int K = q4 * 4 + ti;
        if (more) {
          if ((K & 1) == 0) {
            if (K >= 2) PACKP(sA0, sA1, K - 2, nb);
            LOADP(sA0, sA1, c + 1, K);
          } else {
            if (K >= 2) PACKP(sB0, sB1, K - 2, nb);
            LOADP(sB0, sB1, c + 1, K);
          }
        }
        COMPUTE(cc, K, blo, bhi);
      }
    }
    if (more) {
      PACKP(sA0, sA1, 14, nb);
      PACKP(sB0, sB1, 15, nb);
    }
    __syncthreads();
  }

  // ---- denominator partial (chalf==0 waves only; fold g first) ----
  dsum += __shfl_xor(dsum, 32);
  if (chalf == 0 && l < 32) dred[kpair * 32 + l] = dsum;

  // ---- accumulator reduce: kpair0 stores, kpairs 1..3 add ----
  const int colw = l & 31;
  float* dst0 = &lred[chalf * 64 + colw];
  float* dst1 = &lred[chalf * 64 + 32 + colw];
  if (kpair == 0) {
    st16(dst0, accQ0, g);
    st16(dst1, accQ1, g);
  }
  __syncthreads();
  if (kpair == 1) {
    ad16(dst0, accQ0, g);
    ad16(dst1, accQ1, g);
  }
  __syncthreads();
  if (kpair == 2) {
    ad16(dst0, accQ0, g);
    ad16(dst1, accQ1, g);
  }
  __syncthreads();
  if (kpair == 3) {
    ad16(dst0, accQ0, g);
    ad16(dst1, accQ1, g);
  }
  __syncthreads();

  // ---- write fp32 partial + denominator partial ----
  if (t < 32) {
    float d = dred[t] + dred[32 + t] + dred[64 + t] + dred[96 + t];
    dpart[jh * NN + r0 + t] = d;
  }
  const int flat = t * 8;  // row = t>>4, col = (t&15)*8
  float* pp = part + (size_t)jh * (NN * OUTF) + (size_t)r0 * OUTF + flat;
  *(f32x4*)pp = *(f32x4*)&lred[flat];
  *(f32x4*)(pp + 4) = *(f32x4*)&lred[flat + 4];
}

// ---------------------------------------------------------------------------
// K4: combine 2 partials, divide by denom, elu, store.
// ---------------------------------------------------------------------------
__global__ __launch_bounds__(256) void gat_k4(
    const float* __restrict__ part, const float* __restrict__ dpart,
    float* __restrict__ out) {
  const int idx = blockIdx.x * 256 + threadIdx.x;
  const int e4 = idx * 4;
  const int i = e4 >> 7;
  f32x4 p = *(const f32x4*)&part[e4];
  p += *(const f32x4*)&part[(size_t)(NN * OUTF) + e4];
  float d = dpart[i] + dpart[NN + i];
  d = fmaxf(d, 1e-30f);
  f32x4 r;
#pragma unroll
  for (int k = 0; k < 4; k++) {
    float v = p[k] / d;
    r[k] = (v > 0.f) ? v : expm1f(v);
  }
  *(f32x4*)&out[e4] = r;
}

extern "C" void kernel_launch(void* const* d_in, const int* in_sizes, int n_in,
                              void* d_out, int out_size, void* d_ws, size_t ws_size,
                              hipStream_t stream) {
  (void)in_sizes; (void)n_in; (void)out_size; (void)ws_size;
  const float* X  = (const float*)d_in[0];
  const int*  adj = (const int*)d_in[1];
  const float* W  = (const float*)d_in[2];
  const float* a  = (const float*)d_in[3];
  float* out = (float*)d_out;

  char* ws = (char*)d_ws;
  u16*   hbF   = (u16*)ws;                                  // 2 MB @ 0
  float* s1    = (float*)(ws + (2u << 20));                 // 32 KB
  float* s2    = (float*)(ws + (2u << 20) + (32u << 10));   // 32 KB
  float* bmax  = (float*)(ws + (2u << 20) + (64u << 10));   // 32 B
  float* E1    = (float*)(ws + (2u << 20) + (128u << 10));  // 32 KB
  float* E2    = (float*)(ws + (2u << 20) + (160u << 10));  // 32 KB
  float* dpart = (float*)(ws + (2u << 20) + (192u << 10));  // 64 KB
  float* part  = (float*)(ws + (4u << 20));                 // 8 MB @ 4M

  gat_k1<<<NN / 16, 256, 0, stream>>>(X, W, a, hbF, s1, s2);
  gat_k2<<<8, 256, 0, stream>>>(s2, bmax, E1, E2);
  gat_k3<<<512, 512, 0, stream>>>(adj, hbF, s1, E1, E2, bmax, part, dpart);
  gat_k4<<<(NN * OUTF / 4) / 256, 256, 0, stream>>>(part, dpart, out);
}

// Round 17
// 128.200 us; speedup vs baseline: 2.7407x; 2.7407x over previous
//
#include <hip/hip_runtime.h>
#include <hip/hip_bf16.h>

#define NN   8192
#define INF_ 256
#define OUTF 128
#define SLOPE 0.2f
#define NCH  2               // chunks per block
#define CHJ  1024            // j per chunk
#define NT_  16              // tile-steps per chunk (64 j each across 4 waves)
#define NP_  16              // stage pieces per chunk (64 ints/row each)

typedef float f32x4  __attribute__((ext_vector_type(4)));
typedef float f32x16 __attribute__((ext_vector_type(16)));
typedef short bf16x8 __attribute__((ext_vector_type(8)));
typedef int   i32x4  __attribute__((ext_vector_type(4)));
typedef unsigned int u32;
typedef unsigned short u16;
typedef u16 u16x2 __attribute__((ext_vector_type(2)));

__device__ __forceinline__ u16 f2bf(float f) {
  return __builtin_bit_cast(u16, __float2bfloat16(f));
}

// j mapping: j = cc*1024 + pr*128 + tt*8 + e
//   cc 0..7 global chunk, pr 0..7 = 2w+g (w wave 0..3, g lane>>5), tt 0..15.
// hbF B-frag block n = (cc*16 + tt)*4 + w; element (n,q,l,e) at
//   ((n*4+q)*64 + l)*8 + e  (q = col>>5; lane l: col=l&31, k=(l>>5)*8+e).
// Mask byte (row, cc, pr, tt) at mb[cc&1][row*128 + ((pr^(row&7))<<4) + tt].

// ---------------------------------------------------------------------------
// K1: h = X @ W (fp32). 512 blocks x 16 rows. Writes hbF (B-frag order),
// s1, s2 (plain j order).
// ---------------------------------------------------------------------------
__global__ __launch_bounds__(256) void gat_k1(
    const float* __restrict__ X, const float* __restrict__ W,
    const float* __restrict__ a, u16* __restrict__ hbF,
    float* __restrict__ s1, float* __restrict__ s2) {
  __shared__ float xs[16 * INF_];
  const int t = threadIdx.x;
  const int r0 = blockIdx.x * 16;
  {
    const f32x4* src = (const f32x4*)(X + (size_t)r0 * INF_);
    f32x4* dst = (f32x4*)xs;
#pragma unroll
    for (int i = 0; i < 4; i++) dst[t + 256 * i] = src[t + 256 * i];
  }
  __syncthreads();
  const int cg = t & 31;
  const int rg = t >> 5;
  float acc[2][4];
#pragma unroll
  for (int i = 0; i < 2; i++)
#pragma unroll
    for (int j = 0; j < 4; j++) acc[i][j] = 0.f;

  for (int k = 0; k < INF_; k += 4) {
    f32x4 xv[2];
#pragma unroll
    for (int i = 0; i < 2; i++) xv[i] = *(const f32x4*)&xs[(rg * 2 + i) * INF_ + k];
#pragma unroll
    for (int kk = 0; kk < 4; kk++) {
      f32x4 wv = *(const f32x4*)&W[(k + kk) * OUTF + cg * 4];
#pragma unroll
      for (int i = 0; i < 2; i++)
#pragma unroll
        for (int j = 0; j < 4; j++) acc[i][j] = fmaf(xv[i][kk], wv[j], acc[i][j]);
    }
  }

  f32x4 a1v = *(const f32x4*)&a[cg * 4];
  f32x4 a2v = *(const f32x4*)&a[OUTF + cg * 4];
  float p1[2], p2[2];
#pragma unroll
  for (int i = 0; i < 2; i++) {
    p1[i] = acc[i][0] * a1v[0] + acc[i][1] * a1v[1] + acc[i][2] * a1v[2] + acc[i][3] * a1v[3];
    p2[i] = acc[i][0] * a2v[0] + acc[i][1] * a2v[1] + acc[i][2] * a2v[2] + acc[i][3] * a2v[3];
  }
#pragma unroll
  for (int m = 1; m < 32; m <<= 1) {
#pragma unroll
    for (int i = 0; i < 2; i++) {
      p1[i] += __shfl_xor(p1[i], m);
      p2[i] += __shfl_xor(p2[i], m);
    }
  }
  if (cg == 0) {
#pragma unroll
    for (int i = 0; i < 2; i++) {
      s1[r0 + rg * 2 + i] = p1[i];
      s2[r0 + rg * 2 + i] = p2[i];
    }
  }

  const int R0 = r0 + rg * 2;           // 2-aligned
  const int cc = R0 >> 10;
  const int rest = R0 & 1023;
  const int pr = rest >> 7;
  const int tt = (rest >> 3) & 15;
  const int e0 = R0 & 7;                // even
  const int w_ = pr >> 1;
  const int g_ = pr & 1;
  const int n  = (cc * 16 + tt) * 4 + w_;
#pragma unroll
  for (int j = 0; j < 4; j++) {
    const int C = cg * 4 + j;
    u16x2 pk = {f2bf(acc[0][j]), f2bf(acc[1][j])};
    *(u16x2*)(hbF + ((size_t)(n * 4 + (C >> 5)) * 64 + g_ * 32 + (C & 31)) * 8 + e0) = pk;
  }
}

// ---------------------------------------------------------------------------
// K2: E1 = exp(s2); E2 = exp(SLOPE*s2); bmax[block] = max chunk.
// ---------------------------------------------------------------------------
__global__ __launch_bounds__(256) void gat_k2(const float* __restrict__ s2,
                                              float* __restrict__ bmax,
                                              float* __restrict__ E1,
                                              float* __restrict__ E2) {
  __shared__ float sm[4];
  const int t = threadIdx.x;
  const int i = blockIdx.x * 256 + t;
  f32x4 v = ((const f32x4*)s2)[i];
  f32x4 e1, e2;
  float m = -1e30f;
#pragma unroll
  for (int k = 0; k < 4; k++) {
    m = fmaxf(m, v[k]);
    e1[k] = __expf(v[k]);
    e2[k] = __expf(SLOPE * v[k]);
  }
  ((f32x4*)E1)[i] = e1;
  ((f32x4*)E2)[i] = e2;
#pragma unroll
  for (int k = 1; k < 64; k <<= 1) m = fmaxf(m, __shfl_xor(m, k));
  if ((t & 63) == 0) sm[t >> 6] = m;
  __syncthreads();
  if (t == 0)
    bmax[blockIdx.x] = fmaxf(fmaxf(sm[0], sm[1]), fmaxf(sm[2], sm[3]));
}

// ---------------------------------------------------------------------------
// K3: 1024 blocks x 256 thr (4 waves), launch_bounds(256,4) -> 4 blocks/CU,
// 16 waves/CU — R11's register-proven shape (no spill) + R12's race-free
// chunk-dbuf schedule + R10's lean COMPUTE. Block = 32 rows x 2048 j
// (2 chunks of 1024 j). Compute chunk c while streaming+packing c+1;
// one __syncthreads per chunk (loads all consumed -> free drain).
// ---------------------------------------------------------------------------
__device__ __forceinline__ void st16(float* dst, const f32x16& A, int g) {
#pragma unroll
  for (int r = 0; r < 16; r++) {
    const int dr = (r & 3) + 8 * (r >> 2) + 4 * g;
    dst[dr * 128] = A[r];
  }
}
__device__ __forceinline__ void ad16(float* dst, const f32x16& A, int g) {
#pragma unroll
  for (int r = 0; r < 16; r++) {
    const int dr = (r & 3) + 8 * (r >> 2) + 4 * g;
    dst[dr * 128] += A[r];
  }
}

__global__ __launch_bounds__(256, 4) void gat_k3(
    const int* __restrict__ adj, const u16* __restrict__ hbF,
    const float* __restrict__ s1g, const float* __restrict__ E1,
    const float* __restrict__ E2, const float* __restrict__ bmax,
    float* __restrict__ part, float* __restrict__ dpart) {
  __shared__ unsigned char mb[2][4096];  // mask double-buffer (32 x 128 B)
  __shared__ float lred[4096];           // 16 KB single reduce buffer
  __shared__ float dred[128];
  const int t = threadIdx.x;
  const int w = t >> 6;         // 0..3
  const int l = t & 63;
  const int rb = blockIdx.x >> 2;
  const int jq = blockIdx.x & 3;
  const int r0 = rb * 32;
  const int row = l & 31;
  const int g = l >> 5;
  const int pr = 2 * w + g;     // 0..7: this lane's 128-j window

  // ---- per-row constants ----
  float s2m = bmax[0];
#pragma unroll
  for (int k = 1; k < 8; k++) s2m = fmaxf(s2m, bmax[k]);
  const float s1r = s1g[r0 + row];
  float Mi = s1r + s2m;
  Mi = fmaxf(Mi, SLOPE * Mi);
  const float A = __expf(s1r - Mi);
  const float B = __expf(SLOPE * s1r - Mi);

  // ---- staging ids: srow = t>>3 (0..31), cl = t&7; 8 ints per piece ----
  const int srow = t >> 3;
  const int cl = t & 7;
  const int* gsrc = adj + (size_t)(r0 + srow) * NN + jq * (NCH * CHJ) + cl * 8;

  i32x4 sA0, sA1, sB0, sB1;
#define LOADP(S0, S1, C, P)                        \
  {                                                \
    const int* p_ = gsrc + (C) * CHJ + (P) * 64;   \
    S0 = *(const i32x4*)(p_);                      \
    S1 = *(const i32x4*)(p_ + 4);                  \
  }
#define PACKP(S0, S1, P, NB)                                                 \
  {                                                                          \
    const int idx_ = (P)*8 + cl;                                             \
    const int pr_ = idx_ >> 4;                                               \
    const int tt_ = idx_ & 15;                                               \
    unsigned b_ = 0;                                                         \
    _Pragma("unroll") for (int e_ = 0; e_ < 4; e_++) {                       \
      b_ |= (S0[e_] > 0 ? 1u : 0u) << e_;                                    \
      b_ |= (S1[e_] > 0 ? 1u : 0u) << (e_ + 4);                              \
    }                                                                        \
    mb[NB][srow * 128 + ((pr_ ^ (srow & 7)) << 4) + tt_] = (unsigned char)b_;\
  }

  f32x16 acc0 = 0.f, acc1 = 0.f, acc2 = 0.f, acc3 = 0.f;
  float dsum = 0.f;

#define COMPUTE(CC, TT, BMV)                                                   \
  {                                                                            \
    const unsigned bl_ =                                                       \
        ((unsigned)(BMV)[(TT) >> 2] >> (((TT)&3) * 8)) & 0xffu;                \
    const int n0 = ((CC)*16 + (TT)) * 4 + w;                                   \
    const u16* q0 = hbF + (size_t)n0 * 2048 + l * 8;                           \
    bf16x8 b0 = *(const bf16x8*)(q0);                                          \
    bf16x8 b1 = *(const bf16x8*)(q0 + 512);                                    \
    bf16x8 b2 = *(const bf16x8*)(q0 + 1024);                                   \
    bf16x8 b3 = *(const bf16x8*)(q0 + 1536);                                   \
    const int j0 = (CC)*CHJ + pr * 128 + (TT)*8;                               \
    f32x4 u0 = *(const f32x4*)(E1 + j0);                                       \
    f32x4 u1 = *(const f32x4*)(E1 + j0 + 4);                                   \
    f32x4 v0 = *(const f32x4*)(E2 + j0);                                       \
    f32x4 v1 = *(const f32x4*)(E2 + j0 + 4);                                   \
    u32 aw[4];                                                                 \
    _Pragma("unroll") for (int e = 0; e < 8; e += 2) {                         \
      const float x0 = (e < 4) ? u0[e & 3] : u1[e & 3];                        \
      const float x1 = (e < 4) ? u0[(e + 1) & 3] : u1[(e + 1) & 3];            \
      const float y0 = (e < 4) ? v0[e & 3] : v1[e & 3];                        \
      const float y1 = (e < 4) ? v0[(e + 1) & 3] : v1[(e + 1) & 3];            \
      float pa = fmaxf(A * x0, B * y0);                                        \
      float pb = fmaxf(A * x1, B * y1);                                        \
      pa = (bl_ & (1u << e)) ? pa : 0.f;                                       \
      pb = (bl_ & (1u << (e + 1))) ? pb : 0.f;                                 \
      dsum += pa + pb;                                                         \
      aw[e >> 1] = __builtin_amdgcn_perm(                                      \
          __builtin_bit_cast(u32, pb) + 0x8000u,                               \
          __builtin_bit_cast(u32, pa) + 0x8000u, 0x07060302u);                 \
    }                                                                          \
    const bf16x8 af = __builtin_bit_cast(                                      \
        bf16x8, (i32x4){(int)aw[0], (int)aw[1], (int)aw[2], (int)aw[3]});      \
    acc0 = __builtin_amdgcn_mfma_f32_32x32x16_bf16(af, b0, acc0, 0, 0, 0);     \
    acc1 = __builtin_amdgcn_mfma_f32_32x32x16_bf16(af, b1, acc1, 0, 0, 0);     \
    acc2 = __builtin_amdgcn_mfma_f32_32x32x16_bf16(af, b2, acc2, 0, 0, 0);     \
    acc3 = __builtin_amdgcn_mfma_f32_32x32x16_bf16(af, b3, acc3, 0, 0, 0);     \
  }

  // ---- prologue: stream local chunk 0 into mb[0] (2-pair pipeline) ----
  LOADP(sA0, sA1, 0, 0);
  LOADP(sB0, sB1, 0, 1);
#pragma unroll
  for (int p = 2; p < NP_; p += 2) {
    PACKP(sA0, sA1, p - 2, 0);
    LOADP(sA0, sA1, 0, p);
    PACKP(sB0, sB1, p - 1, 0);
    LOADP(sB0, sB1, 0, p + 1);
  }
  PACKP(sA0, sA1, 14, 0);
  PACKP(sB0, sB1, 15, 0);
  __syncthreads();

  // ---- main: runtime loop over 2 local chunks ----
  for (int c = 0; c < NCH; c++) {
    const int cb = c & 1, nb = cb ^ 1;
    const int cc = jq * NCH + c;        // global chunk id (0..7)
    const i32x4 bmv =
        *(const i32x4*)&mb[cb][row * 128 + ((pr ^ (row & 7)) << 4)];
    const bool more = (c + 1 < NCH);

    for (int K = 0; K < NT_; K++) {
      if (more) {
        if ((K & 1) == 0) {
          if (K >= 2) PACKP(sA0, sA1, K - 2, nb);
          LOADP(sA0, sA1, c + 1, K);
        } else {
          if (K >= 2) PACKP(sB0, sB1, K - 2, nb);
          LOADP(sB0, sB1, c + 1, K);
        }
      }
      COMPUTE(cc, K, bmv);
    }
    if (more) {
      PACKP(sA0, sA1, 14, nb);
      PACKP(sB0, sB1, 15, nb);
    }
    __syncthreads();
  }

  // ---- denominator partial (fold g-halves; per-wave slot) ----
  dsum += __shfl_xor(dsum, 32);
  if (l < 32) dred[w * 32 + l] = dsum;

  // ---- accumulator reduce: wave 0 stores, waves 1..3 add ----
  const int colw = l & 31;
  if (w == 0) {
    st16(&lred[0 * 32 + colw], acc0, g);
    st16(&lred[1 * 32 + colw], acc1, g);
    st16(&lred[2 * 32 + colw], acc2, g);
    st16(&lred[3 * 32 + colw], acc3, g);
  }
  __syncthreads();
  if (w == 1) {
    ad16(&lred[0 * 32 + colw], acc0, g);
    ad16(&lred[1 * 32 + colw], acc1, g);
    ad16(&lred[2 * 32 + colw], acc2, g);
    ad16(&lred[3 * 32 + colw], acc3, g);
  }
  __syncthreads();
  if (w == 2) {
    ad16(&lred[0 * 32 + colw], acc0, g);
    ad16(&lred[1 * 32 + colw], acc1, g);
    ad16(&lred[2 * 32 + colw], acc2, g);
    ad16(&lred[3 * 32 + colw], acc3, g);
  }
  __syncthreads();
  if (w == 3) {
    ad16(&lred[0 * 32 + colw], acc0, g);
    ad16(&lred[1 * 32 + colw], acc1, g);
    ad16(&lred[2 * 32 + colw], acc2, g);
    ad16(&lred[3 * 32 + colw], acc3, g);
  }
  __syncthreads();

  // ---- write fp32 partial + denominator partial ----
  if (t < 32) {
    float d = dred[t] + dred[32 + t] + dred[64 + t] + dred[96 + t];
    dpart[jq * NN + r0 + t] = d;
  }
  const int flat = t * 16;  // row = t>>3, col = (t&7)*16
  float* pp = part + (size_t)jq * (NN * OUTF) + (size_t)r0 * OUTF + flat;
#pragma unroll
  for (int i = 0; i < 4; i++)
    *(f32x4*)(pp + 4 * i) = *(f32x4*)&lred[flat + 4 * i];
}

// ---------------------------------------------------------------------------
// K4: combine 4 partials, divide by denom, elu, store.
// ---------------------------------------------------------------------------
__global__ __launch_bounds__(256) void gat_k4(
    const float* __restrict__ part, const float* __restrict__ dpart,
    float* __restrict__ out) {
  const int idx = blockIdx.x * 256 + threadIdx.x;
  const int e4 = idx * 4;
  const int i = e4 >> 7;
  f32x4 p = {0.f, 0.f, 0.f, 0.f};
  float d = 0.f;
#pragma unroll
  for (int jq = 0; jq < 4; jq++) {
    p += *(const f32x4*)&part[(size_t)jq * (NN * OUTF) + e4];
    d += dpart[jq * NN + i];
  }
  d = fmaxf(d, 1e-30f);
  f32x4 r;
#pragma unroll
  for (int k = 0; k < 4; k++) {
    float v = p[k] / d;
    r[k] = (v > 0.f) ? v : expm1f(v);
  }
  *(f32x4*)&out[e4] = r;
}

extern "C" void kernel_launch(void* const* d_in, const int* in_sizes, int n_in,
                              void* d_out, int out_size, void* d_ws, size_t ws_size,
                              hipStream_t stream) {
  (void)in_sizes; (void)n_in; (void)out_size; (void)ws_size;
  const float* X  = (const float*)d_in[0];
  const int*  adj = (const int*)d_in[1];
  const float* W  = (const float*)d_in[2];
  const float* a  = (const float*)d_in[3];
  float* out = (float*)d_out;

  char* ws = (char*)d_ws;
  u16*   hbF   = (u16*)ws;                                  // 2 MB @ 0
  float* s1    = (float*)(ws + (2u << 20));                 // 32 KB
  float* s2    = (float*)(ws + (2u << 20) + (32u << 10));   // 32 KB
  float* bmax  = (float*)(ws + (2u << 20) + (64u << 10));   // 32 B
  float* E1    = (float*)(ws + (2u << 20) + (128u << 10));  // 32 KB
  float* E2    = (float*)(ws + (2u << 20) + (160u << 10));  // 32 KB
  float* dpart = (float*)(ws + (2u << 20) + (192u << 10));  // 128 KB
  float* part  = (float*)(ws + (4u << 20));                 // 16 MB @ 4M

  gat_k1<<<NN / 16, 256, 0, stream>>>(X, W, a, hbF, s1, s2);
  gat_k2<<<8, 256, 0, stream>>>(s2, bmax, E1, E2);
  gat_k3<<<256 * 4, 256, 0, stream>>>(adj, hbF, s1, E1, E2, bmax, part, dpart);
  gat_k4<<<(NN * OUTF / 4) / 256, 256, 0, stream>>>(part, dpart, out);
}